// Round 3
// baseline (73.591 us; speedup 1.0000x reference)
//
#include <hip/hip_runtime.h>

// out[f, t, lm, k] (F=512, T=1024, LM=12, K=8) fp32:
//   l = lm/4, m = lm%4, s = k+l
//   t < s -> 0
//   fs = (f - s) & 511
//   o  = fs*24 + k*3 + l
//   val = b[o] + sum_{tap} w[o*3+tap] * x[m, t-2+tap, fs]   (negative time taps = 0)
//
// Block = (f, 64-t chunk), 192 threads = 3 waves; wave id == l (uniform per wave).
// Lane = (m, tg): owns 4 consecutive t (t = t0 + tg*4 + dt).
// LDS x slab: x_lds[m][tt][fi], fi=0..11 <-> feature (f-11+fi)&511, tt=0..65 <-> t0-2+tt.
//   per-m stride 796 (66*12=792 +4 pad): b128 bank starts spread -> 2-way (free).
// All per-k selects are compile-time (template<L> + fold expressions).

typedef float f32x4 __attribute__((ext_vector_type(4)));

#define NF 512
#define NT 1024
#define TT 64
#define XROW 12
#define NROWS (TT + 2)   // 66
#define XM 796

template<int...> struct iseq {};
using KS8 = iseq<0,1,2,3,4,5,6,7>;

template<int E>
__device__ __forceinline__ float selx(f32x4 r0, f32x4 r1, f32x4 r2) {
    if constexpr (E < 4)      return r0[E];
    else if constexpr (E < 8) return r1[E - 4];
    else                      return r2[E - 8];
}
template<int K>
__device__ __forceinline__ float selb(f32x4 b0, f32x4 b1) {
    if constexpr (K < 4) return b0[K];
    else                 return b1[K - 4];
}

template<int L, int dt, int tap, int... Ks>
__device__ __forceinline__ void fma8(float (&acc)[4][8], const f32x4 (&wv)[6],
                                     f32x4 r0, f32x4 r1, f32x4 r2, iseq<Ks...>) {
    ((acc[dt][Ks] += wv[(Ks * 3 + tap) >> 2][(Ks * 3 + tap) & 3] *
                     selx<11 - L - Ks>(r0, r1, r2)), ...);
}

template<int dt, int... Ks>
__device__ __forceinline__ void initacc(float (&acc)[4][8], f32x4 b0, f32x4 b1, iseq<Ks...>) {
    ((acc[dt][Ks] = selb<Ks>(b0, b1)), ...);
}

template<int L>
__device__ __forceinline__ void compute_l(const float* __restrict__ x_lds,
                                          const float* __restrict__ w_lds,
                                          const float* __restrict__ b_lds,
                                          float* __restrict__ out,
                                          int f, int t0, int lane)
{
    const int m   = lane & 3;
    const int tg4 = (lane >> 2) * 4;

    // weights/bias for this l: broadcast b128 reads, once per thread
    const f32x4* wp = (const f32x4*)(w_lds + L * 24);
    f32x4 wv[6];
#pragma unroll
    for (int i = 0; i < 6; ++i) wv[i] = wp[i];
    const f32x4* bp = (const f32x4*)(b_lds + L * 8);
    const f32x4 b0 = bp[0], b1 = bp[1];

    float acc[4][8];
    initacc<0>(acc, b0, b1, KS8{});
    initacc<1>(acc, b0, b1, KS8{});
    initacc<2>(acc, b0, b1, KS8{});
    initacc<3>(acc, b0, b1, KS8{});

    // stream 6 rows; row ro covers (dt, tap) with dt + tap == ro
    const f32x4* rp = (const f32x4*)(x_lds + m * XM + tg4 * XROW);
    f32x4 r0, r1, r2;
#define LOADROW r0 = rp[0]; r1 = rp[1]; r2 = rp[2]; rp += 3;
    LOADROW fma8<L,0,0>(acc, wv, r0, r1, r2, KS8{});
    LOADROW fma8<L,1,0>(acc, wv, r0, r1, r2, KS8{});
            fma8<L,0,1>(acc, wv, r0, r1, r2, KS8{});
    LOADROW fma8<L,2,0>(acc, wv, r0, r1, r2, KS8{});
            fma8<L,1,1>(acc, wv, r0, r1, r2, KS8{});
            fma8<L,0,2>(acc, wv, r0, r1, r2, KS8{});
    LOADROW fma8<L,3,0>(acc, wv, r0, r1, r2, KS8{});
            fma8<L,2,1>(acc, wv, r0, r1, r2, KS8{});
            fma8<L,1,2>(acc, wv, r0, r1, r2, KS8{});
    LOADROW fma8<L,3,1>(acc, wv, r0, r1, r2, KS8{});
            fma8<L,2,2>(acc, wv, r0, r1, r2, KS8{});
    LOADROW fma8<L,3,2>(acc, wv, r0, r1, r2, KS8{});
#undef LOADROW

    if (t0 == 0) {  // zero guard t < k+L (only first t-chunk)
#pragma unroll
        for (int dt = 0; dt < 4; ++dt)
#pragma unroll
            for (int k = 0; k < 8; ++k)
                if (tg4 + dt < k + L) acc[dt][k] = 0.0f;
    }

#pragma unroll
    for (int dt = 0; dt < 4; ++dt) {
        const int t = t0 + tg4 + dt;
        float* op = out + ((size_t)(f * NT + t) * 12 + (L * 4 + m)) * 8;
        f32x4 s0 = { acc[dt][0], acc[dt][1], acc[dt][2], acc[dt][3] };
        f32x4 s1 = { acc[dt][4], acc[dt][5], acc[dt][6], acc[dt][7] };
        *(f32x4*)op       = s0;
        *(f32x4*)(op + 4) = s1;
    }
}

__global__ __launch_bounds__(192) void caconv_kernel(
    const float* __restrict__ x,   // [4][1024][512]
    const float* __restrict__ w,   // [12288*3]
    const float* __restrict__ b,   // [12288]
    float* __restrict__ out)       // [512][1024][12][8]
{
    __shared__ float x_lds[4 * XM];
    __shared__ float w_lds[72];
    __shared__ float b_lds[24];

    const int tid = threadIdx.x;
    const int f   = blockIdx.x >> 4;
    const int t0  = (blockIdx.x & 15) * TT;

    // ---- stage w/b, rearranged to [l][k][tap] / [l][k] ----
    if (tid < 72) {
        const int l = tid / 24, r = tid - l * 24, k = r / 3, tap = r - k * 3;
        const int fs = (f - k - l + NF) & (NF - 1);
        w_lds[tid] = w[(fs * 24 + k * 3 + l) * 3 + tap];
    } else if (tid < 96) {
        const int j = tid - 72, l = j >> 3, k = j & 7;
        const int fs = (f - k - l + NF) & (NF - 1);
        b_lds[l * 8 + k] = b[fs * 24 + k * 3 + l];
    }

    // ---- stage x slab: 4m x 66 rows x 12 fi = 3168 floats ----
    for (int i = tid; i < 4 * NROWS * XROW; i += 192) {
        const int fi  = i % 12;
        const int row = i / 12;
        const int tt  = row % 66;
        const int m   = row / 66;
        const int tgl = t0 - 2 + tt;
        const int fs  = (f - 11 + fi + NF) & (NF - 1);
        float v = 0.0f;
        if (tgl >= 0) v = x[((m << 10) + tgl) * NF + fs];
        x_lds[m * XM + tt * XROW + fi] = v;
    }
    __syncthreads();

    const int wid = tid >> 6, lane = tid & 63;
    if (wid == 0)      compute_l<0>(x_lds, w_lds, b_lds, out, f, t0, lane);
    else if (wid == 1) compute_l<1>(x_lds, w_lds, b_lds, out, f, t0, lane);
    else               compute_l<2>(x_lds, w_lds, b_lds, out, f, t0, lane);
}

extern "C" void kernel_launch(void* const* d_in, const int* in_sizes, int n_in,
                              void* d_out, int out_size, void* d_ws, size_t ws_size,
                              hipStream_t stream)
{
    const float* x = (const float*)d_in[0];
    const float* w = (const float*)d_in[1];
    const float* b = (const float*)d_in[2];
    float* out = (float*)d_out;

    const int grid = NF * (NT / TT);   // 8192 blocks
    caconv_kernel<<<grid, 192, 0, stream>>>(x, w, b, out);
}

// Round 4
// 61.214 us; speedup vs baseline: 1.2022x; 1.2022x over previous
//
#include <hip/hip_runtime.h>

// out[f, t, lm, k] (F=512, T=1024, LM=12, K=8) fp32:
//   l = lm/4, m = lm%4, s = k+l ; t < s -> 0
//   fs = (f - s) & 511 ; o = fs*24 + k*3 + l
//   val = b[o] + sum_{tap} w[o*3+tap] * x[m, t-2+tap, fs]   (negative time taps = 0)
//
// Block = (f, 64-t chunk), 384 threads = 6 waves; wave wid: l = wid>>1 (uniform),
// h = wid&1. Lane: m = lane&3, tg = lane>>2; owns t = t0 + h*32 + tg*2 + {0,1}.
// LDS x slab x_lds[m][tt][fi]: XROW=20 (12 used, b128-aligned), XM=1348 (== 4 mod 32)
//   -> per-instr b128 start banks 4m+8(tg&3): all 8 groups x 8 lanes = minimum.
// Weights/bias rearranged [l][k][tap]/[l][k], broadcast b128 into registers.
// All per-k selects compile-time (template<L> + fold expressions) -> no scratch.

typedef float f32x4 __attribute__((ext_vector_type(4)));

#define NF 512
#define NT 1024
#define TT 64
#define XROW 20
#define XM   1348       // 66*20 + 28 pad  (== 4 mod 32, dword count, 16B-multiple)
#define NROWS 66

template<int...> struct iseq {};
using KS8 = iseq<0,1,2,3,4,5,6,7>;

template<int E>
__device__ __forceinline__ float selx(f32x4 r0, f32x4 r1, f32x4 r2) {
    if constexpr (E < 4)      return r0[E];
    else if constexpr (E < 8) return r1[E - 4];
    else                      return r2[E - 8];
}
template<int K>
__device__ __forceinline__ float selb(f32x4 b0, f32x4 b1) {
    if constexpr (K < 4) return b0[K];
    else                 return b1[K - 4];
}

template<int L, int dt, int tap, int... Ks>
__device__ __forceinline__ void fma8(float (&acc)[2][8], const f32x4 (&wv)[6],
                                     f32x4 r0, f32x4 r1, f32x4 r2, iseq<Ks...>) {
    ((acc[dt][Ks] += wv[(Ks * 3 + tap) >> 2][(Ks * 3 + tap) & 3] *
                     selx<11 - L - Ks>(r0, r1, r2)), ...);
}
template<int dt, int... Ks>
__device__ __forceinline__ void initacc(float (&acc)[2][8], f32x4 b0, f32x4 b1, iseq<Ks...>) {
    ((acc[dt][Ks] = selb<Ks>(b0, b1)), ...);
}

template<int L>
__device__ __forceinline__ void compute_l(const float* __restrict__ x_lds,
                                          const float* __restrict__ w_lds,
                                          const float* __restrict__ b_lds,
                                          float* __restrict__ out,
                                          int f, int t0, int h, int lane)
{
    const int m     = lane & 3;
    const int tg    = lane >> 2;           // [0,16)
    const int t_off = h * 32 + tg * 2;

    const f32x4* wp = (const f32x4*)(w_lds + L * 24);
    f32x4 wv[6];
#pragma unroll
    for (int i = 0; i < 6; ++i) wv[i] = wp[i];
    const f32x4* bp = (const f32x4*)(b_lds + L * 8);
    const f32x4 b0 = bp[0], b1 = bp[1];

    float acc[2][8];
    initacc<0>(acc, b0, b1, KS8{});
    initacc<1>(acc, b0, b1, KS8{});

    // rows tt = t_off + ro, ro in [0,4); (dt,tap) pairs with dt+tap == ro
    const f32x4* rp = (const f32x4*)(x_lds + m * XM + t_off * XROW);
    f32x4 r0, r1, r2;

    r0 = rp[0]; r1 = rp[1]; r2 = rp[2]; rp += XROW / 4;
    fma8<L, 0, 0>(acc, wv, r0, r1, r2, KS8{});

    r0 = rp[0]; r1 = rp[1]; r2 = rp[2]; rp += XROW / 4;
    fma8<L, 0, 1>(acc, wv, r0, r1, r2, KS8{});
    fma8<L, 1, 0>(acc, wv, r0, r1, r2, KS8{});

    r0 = rp[0]; r1 = rp[1]; r2 = rp[2]; rp += XROW / 4;
    fma8<L, 0, 2>(acc, wv, r0, r1, r2, KS8{});
    fma8<L, 1, 1>(acc, wv, r0, r1, r2, KS8{});

    r0 = rp[0]; r1 = rp[1]; r2 = rp[2];
    fma8<L, 1, 2>(acc, wv, r0, r1, r2, KS8{});

    if (t0 == 0) {   // zero guard: t < k + L (first chunk only)
#pragma unroll
        for (int dt = 0; dt < 2; ++dt)
#pragma unroll
            for (int k = 0; k < 8; ++k)
                if (t_off + dt < k + L) acc[dt][k] = 0.0f;
    }

#pragma unroll
    for (int dt = 0; dt < 2; ++dt) {
        const int t = t0 + t_off + dt;
        float* op = out + ((size_t)((f << 10) + t) * 12 + (L * 4 + m)) * 8;
        f32x4 s0 = { acc[dt][0], acc[dt][1], acc[dt][2], acc[dt][3] };
        f32x4 s1 = { acc[dt][4], acc[dt][5], acc[dt][6], acc[dt][7] };
        *(f32x4*)op       = s0;
        *(f32x4*)(op + 4) = s1;
    }
}

__global__ __launch_bounds__(384, 4) void caconv_kernel(
    const float* __restrict__ x,   // [4][1024][512]
    const float* __restrict__ w,   // [12288*3]
    const float* __restrict__ b,   // [12288]
    float* __restrict__ out)       // [512][1024][12][8]
{
    __shared__ float x_lds[4 * XM];   // 21.6 KB
    __shared__ float w_lds[72];
    __shared__ float b_lds[24];

    const int tid = threadIdx.x;
    const int f   = blockIdx.x >> 4;
    const int t0  = (blockIdx.x & 15) * TT;

    // ---- stage w/b rearranged to [l][k][tap] / [l][k] ----
    if (tid < 72) {
        const int l = tid / 24, r = tid - l * 24, k = r / 3, tap = r - k * 3;
        const int fs = (f - k - l + NF) & (NF - 1);
        w_lds[tid] = w[(fs * 24 + k * 3 + l) * 3 + tap];
    } else if (tid < 96) {
        const int j = tid - 72, l = j >> 3, k = j & 7;
        const int fs = (f - k - l + NF) & (NF - 1);
        b_lds[l * 8 + k] = b[fs * 24 + k * 3 + l];
    }

    // ---- stage x slab: 4m x 66 rows x 12 fi (into padded rows) ----
    for (int i = tid; i < 4 * NROWS * 12; i += 384) {
        const int fi  = i % 12;
        const int row = i / 12;
        const int tt  = row % NROWS;
        const int m   = row / NROWS;
        const int tgl = t0 - 2 + tt;
        const int fs  = (f - 11 + fi + NF) & (NF - 1);
        float v = 0.0f;
        if (tgl >= 0) v = x[((m << 10) + tgl) * NF + fs];
        x_lds[m * XM + tt * XROW + fi] = v;
    }
    __syncthreads();

    const int wid = tid >> 6, lane = tid & 63;
    const int l = wid >> 1, h = wid & 1;
    if (l == 0)      compute_l<0>(x_lds, w_lds, b_lds, out, f, t0, h, lane);
    else if (l == 1) compute_l<1>(x_lds, w_lds, b_lds, out, f, t0, h, lane);
    else             compute_l<2>(x_lds, w_lds, b_lds, out, f, t0, h, lane);
}

extern "C" void kernel_launch(void* const* d_in, const int* in_sizes, int n_in,
                              void* d_out, int out_size, void* d_ws, size_t ws_size,
                              hipStream_t stream)
{
    const float* x = (const float*)d_in[0];
    const float* w = (const float*)d_in[1];
    const float* b = (const float*)d_in[2];
    float* out = (float*)d_out;

    const int grid = NF * (NT / TT);   // 8192 blocks
    caconv_kernel<<<grid, 384, 0, stream>>>(x, w, b, out);
}

// Round 6
// 48.209 us; speedup vs baseline: 1.5265x; 1.2698x over previous
//
#include <hip/hip_runtime.h>

// out[f, t, lm, k] (F=512, T=1024, LM=12, K=8) fp32:
//   l = lm/4, m = lm%4, s = k+l ; t < s -> 0
//   fs = (f - s) & 511 ; o = fs*24 + k*3 + l
//   val = b[o] + sum_{tap} w[o*3+tap] * x[m, t-2+tap, fs]   (negative time taps = 0)
//
// Block = (f, 64-t tile), 256 threads. The tile's output is 24 KB CONTIGUOUS.
// Lane -> flat float4 chunk c = tid + 256*j (j=0..5): every wave store instr is
// 1024 B fully dense (fill-kernel pattern) -- attacks write-transaction limit.
// chunk c: kh=c&1 (k-half), q=c>>1, lm=q%12, t_off=q/12; k = 4*kh + kk.
// LDS: x_lds[m][tt][fi] fi=0..11 <-> fs=(f-11+fi)&511, tt <-> t0-2+tt; XM=808
// ( ==8 mod 32 -> bank spread for scalar reads). Weights re-staged [l][tap][k]
// (k contiguous, 16B-aligned b128 reads); bias [l][k].
// x value for (k,l): fi = 11-(k+l); chunk reads 4 consecutive fi per tap ->
// consecutive-dword LDS reads (compiler merges to ds_read2_b32).
// #pragma unroll 1 keeps VGPR low (target <=64 -> 8 waves/SIMD, round-2 regime).

typedef float f32x4 __attribute__((ext_vector_type(4)));

#define NF 512
#define NT 1024
#define TT 64
#define XROW 12
#define NROWS 66
#define XM 808          // 66*12 + 16 pad; XM % 32 == 8, 16B-multiple

__global__ __launch_bounds__(256) void caconv_kernel(
    const float* __restrict__ x,   // [4][1024][512]
    const float* __restrict__ w,   // [12288*3]
    const float* __restrict__ b,   // [12288]
    float* __restrict__ out)       // [512][1024][12][8]
{
    __shared__ float x_lds[4 * XM];   // 12.9 KB
    __shared__ float w_lds[72];       // [l][tap][k]
    __shared__ float b_lds[24];       // [l][k]

    const int tid = threadIdx.x;
    const int f   = blockIdx.x >> 4;
    const int t0  = (blockIdx.x & 15) * TT;

    // ---- stage w (transposed to [l][tap][k]) and b ([l][k]) ----
    if (tid < 72) {
        const int l = tid / 24, r = tid - l * 24, tap = r >> 3, k = r & 7;
        const int fs = (f - k - l + NF) & (NF - 1);
        w_lds[tid] = w[(fs * 24 + k * 3 + l) * 3 + tap];   // dst = l*24+tap*8+k
    } else if (tid < 96) {
        const int j = tid - 72, l = j >> 3, k = j & 7;
        const int fs = (f - k - l + NF) & (NF - 1);
        b_lds[j] = b[fs * 24 + k * 3 + l];
    }

    // ---- stage x slab: 4m x 66 rows x 12 fi ----
    for (int i = tid; i < 4 * NROWS * XROW; i += 256) {
        const int fi  = i % 12;
        const int row = i / 12;
        const int tt  = row % NROWS;
        const int m   = row / NROWS;
        const int tg  = t0 - 2 + tt;
        const int fs  = (f - 11 + fi + NF) & (NF - 1);
        float v = 0.0f;
        if (tg >= 0) v = x[((m << 10) + tg) * NF + fs];
        x_lds[m * XM + tt * XROW + fi] = v;
    }
    __syncthreads();

    float* const outb = out + ((size_t)f * NT + t0) * 96;   // block tile base

    // initial chunk decode: c = tid, q = c>>1
    const int kh = tid & 1;
    const int k0 = kh << 2;
    int q     = tid >> 1;          // [0,128)
    int t_off = q / 12;
    int lm    = q - t_off * 12;

#pragma unroll 1
    for (int j = 0; j < 6; ++j) {
        const int l = lm >> 2, m = lm & 3;

        // weights/bias: b128 reads, all 16B-aligned (offsets multiple of 4 dwords)
        const float* wp = w_lds + l * 24 + k0;
        const f32x4 w0 = *(const f32x4*)(wp);        // tap 0, k0..k0+3
        const f32x4 w1 = *(const f32x4*)(wp + 8);    // tap 1
        const f32x4 w2 = *(const f32x4*)(wp + 16);   // tap 2
        f32x4 acc = *(const f32x4*)(b_lds + l * 8 + k0);

        // x rows: base fi = 8 - l - k0 (4 consecutive dwords per tap)
        // fi = base + i  <->  k = k0 + 3 - i   (fi = 11 - l - k)
        const float* xp = x_lds + m * XM + t_off * XROW + (8 - l - k0);

        {
            const float r0 = xp[0], r1 = xp[1], r2 = xp[2], r3 = xp[3];
            acc[0] += w0[0] * r3; acc[1] += w0[1] * r2;
            acc[2] += w0[2] * r1; acc[3] += w0[3] * r0;
        }
        {
            const float r0 = xp[12], r1 = xp[13], r2 = xp[14], r3 = xp[15];
            acc[0] += w1[0] * r3; acc[1] += w1[1] * r2;
            acc[2] += w1[2] * r1; acc[3] += w1[3] * r0;
        }
        {
            const float r0 = xp[24], r1 = xp[25], r2 = xp[26], r3 = xp[27];
            acc[0] += w2[0] * r3; acc[1] += w2[1] * r2;
            acc[2] += w2[2] * r1; acc[3] += w2[3] * r0;
        }

        if (t0 == 0 && t_off < 9) {   // zero guard: t < k + l (first tile only)
#pragma unroll
            for (int kk = 0; kk < 4; ++kk)
                if (t_off < k0 + kk + l) acc[kk] = 0.0f;
        }

        // dense store: chunk c = tid + 256*j -> dword offset (t_off*12+lm)*8 + k0
        *(f32x4*)(outb + (t_off * 12 + lm) * 8 + k0) = acc;

        // next chunk: q += 128  (lm += 8, t_off += 10, carry)
        lm += 8; t_off += 10;
        if (lm >= 12) { lm -= 12; ++t_off; }
    }
}

extern "C" void kernel_launch(void* const* d_in, const int* in_sizes, int n_in,
                              void* d_out, int out_size, void* d_ws, size_t ws_size,
                              hipStream_t stream)
{
    const float* x = (const float*)d_in[0];
    const float* w = (const float*)d_in[1];
    const float* b = (const float*)d_in[2];
    float* out = (float*)d_out;

    const int grid = NF * (NT / TT);   // 8192 blocks
    caconv_kernel<<<grid, 256, 0, stream>>>(x, w, b, out);
}